// Round 18
// baseline (225.789 us; speedup 1.0000x reference)
//
#include <hip/hip_runtime.h>

typedef __attribute__((ext_vector_type(8))) _Float16 half8;
typedef __attribute__((ext_vector_type(4))) _Float16 half4v;
typedef __attribute__((ext_vector_type(4))) float float4v;
typedef __attribute__((ext_vector_type(4))) unsigned int uint4v;
typedef float float4u __attribute__((ext_vector_type(4), aligned(4)));
typedef unsigned long long u64;
typedef unsigned int u32;

#define NB   32
#define CIN  64
#define COUT 128
#define TT   300
#define VV   25
#define EPS  1e-5f
#define M_TOT 240000.0f
#define NBLK 1600
#define NTILE 4800

// ws byte offsets
#define WS_WF    0         // half [8 og][8 kt][64 l][8 j] = 65536 B (unscaled)
#define WS_AEF   65536     // half [4 k][2 nt][64 l][8 j]  = 8192 B (k=3 identity)
#define WS_ST    73728     // float[512]: sH,sH2,sR,sR2 x 128
#define WS_CF    75776     // float[384]: scH, scR, bC
#define WS_WF2   77312     // half [8][8][64][8] = 65536 B (scaled, fallback pass1)
#define WS_TRASH 143360    // 64 B dump for out-of-range uniform stores
// HR: lane-interleaved packed: [tile][grp 4][ H 3584B | R 3584B ] = 28672 B/tile
//   group offsets (within H or R): cm even: (cm>>1)*1024 + on*512 (64 lanes x 8B)
//                                  cm odd : 2048 + (cm>>1)*768 + on*384 (48 lanes x 8B)
#define WS_HR    1048576   // 137625600 B
#define WS_PARTP (WS_HR + 137625600)   // float[1600][512]
#define WS_NEED  (WS_PARTP + 3276800)

// LDS-only barrier: drain lgkm, leave VMEM in flight.
__device__ __forceinline__ void bar_lds() {
    __builtin_amdgcn_sched_barrier(0);
    asm volatile("s_waitcnt lgkmcnt(0)" ::: "memory");
    __builtin_amdgcn_s_barrier();
    __builtin_amdgcn_sched_barrier(0);
}

__device__ __forceinline__ unsigned short f2h(float f) {
    return __builtin_bit_cast(unsigned short, (_Float16)f);
}
__device__ __forceinline__ float4v mfma16(half8 a, half8 b, float4v c) {
    return __builtin_amdgcn_mfma_f32_16x16x32_f16(a, b, c, 0, 0, 0);
}
__device__ __forceinline__ u32 pk2(float a, float b) {
    return __builtin_bit_cast(u32, __builtin_amdgcn_cvt_pkrtz(a, b));
}
__device__ __forceinline__ int hr_off(int cm, int on) {
    return (cm & 1) ? (2048 + (cm >> 1) * 768 + on * 384)
                    : ((cm >> 1) * 1024 + on * 512);
}

__global__ void prep_kernel(const float* __restrict__ A, const float* __restrict__ ga,
                            const float* __restrict__ Wg, const float* __restrict__ Wr,
                            char* __restrict__ wsb) {
    unsigned short* wf = (unsigned short*)(wsb + WS_WF);
    unsigned short* ae = (unsigned short*)(wsb + WS_AEF);
    float* st = (float*)(wsb + WS_ST);
    int i = blockIdx.x * blockDim.x + threadIdx.x;
    for (; i < 32768 + 4096 + 512; i += gridDim.x * blockDim.x) {
        if (i < 32768) {
            int og = i >> 12, kt = (i >> 9) & 7, l = (i >> 3) & 63, j = i & 7;
            int o = og * 16 + (l & 15);
            int kc = kt * 32 + ((l >> 4) << 3) + j;
            float v = (kc < 192) ? Wg[((kc >> 6) * COUT + o) * CIN + (kc & 63)]
                                 : Wr[o * CIN + (kc - 192)];
            wf[i] = f2h(v);
        } else if (i < 32768 + 4096) {
            int q = i - 32768;
            int k = q >> 10, nt = (q >> 9) & 1, l = (q >> 3) & 63, j = q & 7;
            int v = ((l >> 4) << 3) + j, w = nt * 16 + (l & 15);
            float val = 0.0f;
            if (v < VV && w < VV)
                val = (k < 3) ? A[(k * VV + v) * VV + w] * ga[(k * VV + v) * VV + w]
                              : (v == w ? 1.0f : 0.0f);
            ae[q] = f2h(val);
        } else {
            st[i - 36864] = 0.0f;
        }
    }
}

__global__ __launch_bounds__(256) void red_kernel(const float* __restrict__ part,
                                                  char* __restrict__ wsb) {
    float* st = (float*)(wsb + WS_ST);
    __shared__ float red[4][4];
    const int tid = threadIdx.x, wv = tid >> 6, lane = tid & 63;
    const int i0 = blockIdx.x * 4;
    const int bi = tid >> 2, ii = tid & 3;
    float s = 0.0f;
    for (int b = bi; b < NBLK; b += 64)
        s += part[(size_t)b * 512 + i0 + ii];
    s += __shfl_xor(s, 4);
    s += __shfl_xor(s, 8);
    s += __shfl_xor(s, 16);
    s += __shfl_xor(s, 32);
    if (lane < 4) red[wv][lane] = s;
    __syncthreads();
    if (tid < 4) st[i0 + tid] = red[0][tid] + red[1][tid] + red[2][tid] + red[3][tid];
}

__global__ __launch_bounds__(256) void scale_kernel(
        const float* __restrict__ Wg, const float* __restrict__ Wr,
        const float* __restrict__ g1, const float* __restrict__ b1,
        const float* __restrict__ g2, const float* __restrict__ b2,
        char* __restrict__ wsb, int fillw2) {
    const float* st = (const float*)(wsb + WS_ST);
    float* cf = (float*)(wsb + WS_CF);
    unsigned short* wf2 = (unsigned short*)(wsb + WS_WF2);
    __shared__ float cl[384];
    int tid = threadIdx.x;
    if (tid < 128) {
        int o = tid;
        const float inv_m = 1.0f / M_TOT;
        float mH = st[o] * inv_m,        vH = st[128 + o] * inv_m - mH * mH;
        float mR = st[256 + o] * inv_m,  vR = st[384 + o] * inv_m - mR * mR;
        float scH = g1[o] * rsqrtf(vH + EPS);
        float scR = g2[o] * rsqrtf(vR + EPS);
        float bC  = b1[o] + b2[o] - scH * mH - scR * mR;
        cl[o] = scH; cl[128 + o] = scR; cl[256 + o] = bC;
        if (blockIdx.x == 0) { cf[o] = scH; cf[128 + o] = scR; cf[256 + o] = bC; }
    }
    __syncthreads();
    if (!fillw2) return;
    for (int i = blockIdx.x * 256 + tid; i < 32768; i += gridDim.x * 256) {
        int og = i >> 12, kt = (i >> 9) & 7, l = (i >> 3) & 63, j = i & 7;
        int o = og * 16 + (l & 15);
        int kc = kt * 32 + ((l >> 4) << 3) + j;
        float v = (kc < 192) ? Wg[((kc >> 6) * COUT + o) * CIN + (kc & 63)] * cl[o]
                             : Wr[o * CIN + (kc - 192)] * cl[128 + o];
        wf2[i] = f2h(v);
    }
}

// 512 threads (8 waves): wave w owns o-slice [w*16, w*16+16); stage1 split by t = w>>2.
// MODE 0: stats only. MODE 1: fused-BN recompute -> out. MODE 2: stats + coalesced HR store.
template <int MODE>
__global__ __launch_bounds__(512, 4) void gcn_kernel(
        const float* __restrict__ x, char* __restrict__ wsb, float* __restrict__ out,
        float* __restrict__ part) {
    __shared__ __align__(16) _Float16 xa[64 * 256];   // [col][kc], XOR-swizzled, 32768 B
    char* xab = (char*)xa;

    const unsigned short* wf = (const unsigned short*)(wsb + (MODE == 1 ? WS_WF2 : WS_WF));
    const unsigned short* ae = (const unsigned short*)(wsb + WS_AEF);
    const float* cf = (const float*)(wsb + WS_CF);

    const int tid = threadIdx.x, w = tid >> 6, l = tid & 63;
    const int l15 = l & 15, lq = l >> 4;
    const int wv4 = w & 3, tloc = w >> 2;

    // stage2 weights: single o-group = w
    half8 af[8];
#pragma unroll
    for (int kt = 0; kt < 8; ++kt)
        af[kt] = *(const half8*)&wf[((w * 8 + kt) * 64 + l) * 8];

    half8 aef[4][2];
#pragma unroll
    for (int k = 0; k < 4; ++k)
#pragma unroll
        for (int nt = 0; nt < 2; ++nt)
            aef[k][nt] = *(const half8*)&ae[((k * 2 + nt) * 64 + l) * 8];

    float bC2;
    if (MODE == 1) bC2 = cf[256 + w * 16 + l15];

    float sH = 0, sH2 = 0, sR = 0, sR2 = 0;

    // Direct global->reg xf staging: lane covers x[c = wv4*16+l15][t = tloc][v = 8lq..8lq+7].
    const int cRow = wv4 * 16 + l15;
    const int va = (lq * 8 > 16) ? 16 : lq * 8;
    float4u A1, A2;
    float Bv;
    auto ld_tile = [&](int tl) {
        int n_ = tl / 150, t0_ = (tl % 150) * 2;
        const float* base = x + n_ * 480000 + cRow * 7500 + (t0_ + tloc) * 25;
        A1 = *(const float4u*)(base + va);
        A2 = *(const float4u*)(base + va + 4);
        Bv = base[24];
    };
    auto mk_xf = [&]() -> half8 {
        u32 w0 = pk2(A1[0], A1[1]), w1 = pk2(A1[2], A1[3]);
        u32 w2 = pk2(A2[0], A2[1]), w3 = pk2(A2[2], A2[3]);
        if (lq == 3) { w0 = pk2(Bv, 0.0f); w1 = 0; w2 = 0; w3 = 0; }
        uint4v uw = {w0, w1, w2, w3};
        return __builtin_bit_cast(half8, uw);
    };

    // XCD-bijective swizzle (1600 % 8 == 0).
    const int swb = (blockIdx.x & 7) * (NBLK / 8) + (blockIdx.x >> 3);
    const int tile0 = swb * 3;
    ld_tile(tile0);

    for (int it = 0; it < 3; ++it) {
        const int tile = tile0 + it;
        const int n = tile / 150, t0 = (tile % 150) * 2;
        bar_lds();  // xa free (prev stage2 reads done)

        half8 xf = mk_xf();
        if (it < 2) ld_tile(tile + 1);   // prefetch (regs consumed by mk_xf)

        // ---- stage1: wave w writes its t=tloc, kc rows wv4*16.. (k=3 identity -> raw X) ----
#pragma unroll
        for (int k = 0; k < 4; ++k)
#pragma unroll
            for (int nt = 0; nt < 2; ++nt) {
                float4v c4 = {0.0f, 0.0f, 0.0f, 0.0f};
                c4 = mfma16(xf, aef[k][nt], c4);
                int col = tloc * 32 + nt * 16 + l15;
                int kcb = (k * 64 + wv4 * 16 + lq * 4) * 2;
                u64 pk = ((u64)pk2(c4[2], c4[3]) << 32) | pk2(c4[0], c4[1]);
                *(u64*)(xab + ((col << 9) + (kcb ^ ((col & 7) << 4)))) = pk;
            }
        bar_lds();  // xa ready

        char* hrw = wsb + WS_HR + (size_t)tile * 28672 + (w >> 1) * 7168;  // R at +3584
        const int on = w & 1;

        // ---- stage2 (transposed): C[col][o], single o-group per wave ----
        float4v acc[4];
        if (MODE != 1) {
#pragma unroll
            for (int cm = 0; cm < 4; ++cm) acc[cm] = {0.0f, 0.0f, 0.0f, 0.0f};
            __builtin_amdgcn_s_setprio(1);
#pragma unroll
            for (int kt = 0; kt < 6; ++kt)
#pragma unroll
                for (int cm = 0; cm < 4; ++cm) {
                    int col = cm * 16 + l15;
                    half8 bf = *(const half8*)(xab + ((col << 9) +
                                   ((kt * 64 + lq * 16) ^ ((col & 7) << 4))));
                    acc[cm] = mfma16(bf, af[kt], acc[cm]);
                }
            __builtin_amdgcn_s_setprio(0);
            // H flush: stats + uniform lane-interleaved store (MODE 2)
#pragma unroll
            for (int cm = 0; cm < 4; ++cm) {
#pragma unroll
                for (int r = 0; r < 4; ++r) {
                    float h = acc[cm][r];
                    sH += h; sH2 += h * h;
                }
                if (MODE == 2) {
                    u64 p = (u64)pk2(acc[cm][0], acc[cm][1]) |
                            ((u64)pk2(acc[cm][2], acc[cm][3]) << 32);
                    char* dst = hrw + hr_off(cm, on) + l * 8;
                    if ((cm & 1) && lq == 3) dst = wsb + WS_TRASH;
                    *(u64*)dst = p;
                }
                acc[cm] = {0.0f, 0.0f, 0.0f, 0.0f};
            }
            __builtin_amdgcn_s_setprio(1);
#pragma unroll
            for (int kt = 6; kt < 8; ++kt)
#pragma unroll
                for (int cm = 0; cm < 4; ++cm) {
                    int col = cm * 16 + l15;
                    half8 bf = *(const half8*)(xab + ((col << 9) +
                                   ((kt * 64 + lq * 16) ^ ((col & 7) << 4))));
                    acc[cm] = mfma16(bf, af[kt], acc[cm]);
                }
            __builtin_amdgcn_s_setprio(0);
            // R flush
#pragma unroll
            for (int cm = 0; cm < 4; ++cm) {
#pragma unroll
                for (int r = 0; r < 4; ++r) {
                    float rv = acc[cm][r];
                    sR += rv; sR2 += rv * rv;
                }
                if (MODE == 2) {
                    u64 p = (u64)pk2(acc[cm][0], acc[cm][1]) |
                            ((u64)pk2(acc[cm][2], acc[cm][3]) << 32);
                    char* dst = hrw + 3584 + hr_off(cm, on) + l * 8;
                    if ((cm & 1) && lq == 3) dst = wsb + WS_TRASH;
                    *(u64*)dst = p;
                }
            }
        } else {
#pragma unroll
            for (int cm = 0; cm < 4; ++cm)
#pragma unroll
                for (int r = 0; r < 4; ++r) acc[cm][r] = bC2;
            __builtin_amdgcn_s_setprio(1);
#pragma unroll
            for (int kt = 0; kt < 8; ++kt)
#pragma unroll
                for (int cm = 0; cm < 4; ++cm) {
                    int col = cm * 16 + l15;
                    half8 bf = *(const half8*)(xab + ((col << 9) +
                                   ((kt * 64 + lq * 16) ^ ((col & 7) << 4))));
                    acc[cm] = mfma16(bf, af[kt], acc[cm]);
                }
            __builtin_amdgcn_s_setprio(0);
#pragma unroll
            for (int cm = 0; cm < 4; ++cm) {
                int t = t0 + (cm >> 1);
                int o = w * 16 + l15;
                float* op = out + ((size_t)(n * COUT + o) * TT + t) * VV;
                if (!(cm & 1)) {
                    *(float4u*)(op + lq * 4) = acc[cm];
                } else if (lq < 2) {
                    *(float4u*)(op + 16 + lq * 4) = acc[cm];
                } else if (lq == 2) {
                    op[24] = acc[cm][0];
                }
            }
        }
    }

    if (MODE != 1) {
        sH  += __shfl_xor(sH, 16);  sH  += __shfl_xor(sH, 32);
        sH2 += __shfl_xor(sH2, 16); sH2 += __shfl_xor(sH2, 32);
        sR  += __shfl_xor(sR, 16);  sR  += __shfl_xor(sR, 32);
        sR2 += __shfl_xor(sR2, 16); sR2 += __shfl_xor(sR2, 32);
        if (l < 16) {
            float* pb = part + (size_t)blockIdx.x * 512;
            int o = w * 16 + l15;
            pb[o]       = sH;
            pb[128 + o] = sH2;
            pb[256 + o] = sR;
            pb[384 + o] = sR2;
        }
    }
}

// BN apply: block per tile. Coalesced u64 load of 28672 B -> LDS, then linear out writes.
__global__ __launch_bounds__(256) void bn_apply(const char* __restrict__ wsb,
                                                float* __restrict__ out) {
    __shared__ u64 lds[3584];
    const float* cf = (const float*)(wsb + WS_CF);
    const int tile = blockIdx.x;
    const int n = tile / 150, t0 = (tile % 150) * 2;
    const int tid = threadIdx.x;

    const u64* src = (const u64*)(wsb + WS_HR + (size_t)tile * 28672);
#pragma unroll
    for (int i = 0; i < 14; ++i) lds[tid + i * 256] = src[tid + i * 256];
    __syncthreads();

#pragma unroll
    for (int i = 0; i < 7; ++i) {
        int j2 = tid + i * 256;
        int row = j2 / 7, q = j2 - row * 7;
        int o = row >> 1, t = row & 1;
        int v0 = (q < 6) ? q * 4 : 24;
        int cm = t * 2 + (v0 >> 4);
        int lq = (v0 & 15) >> 2;
        int ll = lq * 16 + (o & 15);
        int wv = o >> 5, on = (o >> 4) & 1;
        int offq = (cm & 1) ? (256 + (cm >> 1) * 96 + on * 48)
                            : ((cm >> 1) * 128 + on * 64);
        u64 h64 = lds[wv * 896 + offq + ll];
        u64 r64 = lds[wv * 896 + 448 + offq + ll];
        half4v h4 = __builtin_bit_cast(half4v, h64);
        half4v r4 = __builtin_bit_cast(half4v, r64);
        float scH = cf[o], scR = cf[128 + o], bC = cf[256 + o];
        float* op = out + ((size_t)(n * COUT + o) * TT + t0 + t) * VV + v0;
        if (q < 6) {
            float4u v;
#pragma unroll
            for (int k = 0; k < 4; ++k)
                v[k] = scH * (float)h4[k] + scR * (float)r4[k] + bC;
            *(float4u*)op = v;
        } else {
            op[0] = scH * (float)h4[0] + scR * (float)r4[0] + bC;
        }
    }
}

extern "C" void kernel_launch(void* const* d_in, const int* in_sizes, int n_in,
                              void* d_out, int out_size, void* d_ws, size_t ws_size,
                              hipStream_t stream) {
    const float* x        = (const float*)d_in[0];
    const float* A        = (const float*)d_in[1];
    const float* ga       = (const float*)d_in[2];
    const float* Wg       = (const float*)d_in[3];
    const float* bn_gamma = (const float*)d_in[5];
    const float* bn_beta  = (const float*)d_in[6];
    const float* Wr       = (const float*)d_in[7];
    const float* rbn_g    = (const float*)d_in[9];
    const float* rbn_b    = (const float*)d_in[10];
    char* wsb  = (char*)d_ws;
    float* out = (float*)d_out;

    const bool primary = ws_size >= (size_t)WS_NEED + 4096;
    float* partP = (float*)(wsb + WS_PARTP);
    float* partF = (float*)(wsb + WS_HR);

    prep_kernel<<<64, 256, 0, stream>>>(A, ga, Wg, Wr, wsb);
    if (primary) {
        gcn_kernel<2><<<NBLK, 512, 0, stream>>>(x, wsb, nullptr, partP);
        red_kernel<<<128, 256, 0, stream>>>(partP, wsb);
        scale_kernel<<<64, 256, 0, stream>>>(Wg, Wr, bn_gamma, bn_beta, rbn_g, rbn_b, wsb, 0);
        bn_apply<<<NTILE, 256, 0, stream>>>(wsb, out);
    } else {
        gcn_kernel<0><<<NBLK, 512, 0, stream>>>(x, wsb, nullptr, partF);
        red_kernel<<<128, 256, 0, stream>>>(partF, wsb);
        scale_kernel<<<64, 256, 0, stream>>>(Wg, Wr, bn_gamma, bn_beta, rbn_g, rbn_b, wsb, 1);
        gcn_kernel<1><<<NBLK, 512, 0, stream>>>(x, wsb, out, partF);
    }
}

// Round 19
// 120.201 us; speedup vs baseline: 1.8784x; 1.8784x over previous
//
#include <hip/hip_runtime.h>

typedef __attribute__((ext_vector_type(8))) _Float16 half8;
typedef __attribute__((ext_vector_type(4))) _Float16 half4v;
typedef __attribute__((ext_vector_type(4))) float float4v;
typedef float float4u __attribute__((ext_vector_type(4), aligned(4)));
typedef unsigned long long u64;
typedef unsigned int u32;

#define NB   32
#define CIN  64
#define COUT 128
#define TT   300
#define VV   25
#define EPS  1e-5f
#define M_TOT 240000.0f
#define NBLK 1600
#define NTILE 4800

// ws byte offsets
#define WS_WF    0         // half [8 on][8 kt][64 l][8 j] = 65536 B (unscaled)
#define WS_AEF   65536     // half [4 k][2 nt][64 l][8 j]  = 8192 B (k=3 identity)
#define WS_ST    73728     // float[512]: sH,sH2,sR,sR2 x 128
#define WS_CF    75776     // float[384]: scH, scR, bC
#define WS_WF2   77312     // half [8][8][64][8] = 65536 B (scaled, fallback pass1)
// HR: lane-interleaved packed: [tile][wave 4][ H 3584B | R 3584B ] = 28672 B/tile
//   group offsets (bytes, within H or R): cm even: (cm>>1)*1024 + on*512 (64 lanes x 8B)
//                                         cm odd : 2048 + (cm>>1)*768 + on*384 (48 lanes x 8B)
#define WS_HR    1048576   // 137625600 B
#define WS_PARTP (WS_HR + 137625600)   // float[1600][512]
#define WS_NEED  (WS_PARTP + 3276800)

// LDS-only barrier: drain lgkm, leave VMEM in flight.
__device__ __forceinline__ void bar_lds() {
    __builtin_amdgcn_sched_barrier(0);
    asm volatile("s_waitcnt lgkmcnt(0)" ::: "memory");
    __builtin_amdgcn_s_barrier();
    __builtin_amdgcn_sched_barrier(0);
}

__device__ __forceinline__ unsigned short f2h(float f) {
    return __builtin_bit_cast(unsigned short, (_Float16)f);
}
__device__ __forceinline__ float4v mfma16(half8 a, half8 b, float4v c) {
    return __builtin_amdgcn_mfma_f32_16x16x32_f16(a, b, c, 0, 0, 0);
}
__device__ __forceinline__ u32 pk2(float a, float b) {
    return __builtin_bit_cast(u32, __builtin_amdgcn_cvt_pkrtz(a, b));
}
__device__ __forceinline__ int hr_off(int cm, int on) {  // byte offset within H (or R) block
    return (cm & 1) ? (2048 + (cm >> 1) * 768 + on * 384)
                    : ((cm >> 1) * 1024 + on * 512);
}

__global__ void prep_kernel(const float* __restrict__ A, const float* __restrict__ ga,
                            const float* __restrict__ Wg, const float* __restrict__ Wr,
                            char* __restrict__ wsb) {
    unsigned short* wf = (unsigned short*)(wsb + WS_WF);
    unsigned short* ae = (unsigned short*)(wsb + WS_AEF);
    float* st = (float*)(wsb + WS_ST);
    int i = blockIdx.x * blockDim.x + threadIdx.x;
    for (; i < 32768 + 4096 + 512; i += gridDim.x * blockDim.x) {
        if (i < 32768) {
            int on = i >> 12, kt = (i >> 9) & 7, l = (i >> 3) & 63, j = i & 7;
            int o = on * 16 + (l & 15);
            int kc = kt * 32 + ((l >> 4) << 3) + j;
            float v = (kc < 192) ? Wg[((kc >> 6) * COUT + o) * CIN + (kc & 63)]
                                 : Wr[o * CIN + (kc - 192)];
            wf[i] = f2h(v);
        } else if (i < 32768 + 4096) {
            int q = i - 32768;
            int k = q >> 10, nt = (q >> 9) & 1, l = (q >> 3) & 63, j = q & 7;
            int v = ((l >> 4) << 3) + j, w = nt * 16 + (l & 15);
            float val = 0.0f;
            if (v < VV && w < VV)
                val = (k < 3) ? A[(k * VV + v) * VV + w] * ga[(k * VV + v) * VV + w]
                              : (v == w ? 1.0f : 0.0f);
            ae[q] = f2h(val);
        } else {
            st[i - 36864] = 0.0f;
        }
    }
}

// Reduce part[1600][512] -> st[512].
__global__ __launch_bounds__(256) void red_kernel(const float* __restrict__ part,
                                                  char* __restrict__ wsb) {
    float* st = (float*)(wsb + WS_ST);
    __shared__ float red[4][4];
    const int tid = threadIdx.x, wv = tid >> 6, lane = tid & 63;
    const int i0 = blockIdx.x * 4;
    const int bi = tid >> 2, ii = tid & 3;
    float s = 0.0f;
    for (int b = bi; b < NBLK; b += 64)
        s += part[(size_t)b * 512 + i0 + ii];
    s += __shfl_xor(s, 4);
    s += __shfl_xor(s, 8);
    s += __shfl_xor(s, 16);
    s += __shfl_xor(s, 32);
    if (lane < 4) red[wv][lane] = s;
    __syncthreads();
    if (tid < 4) st[i0 + tid] = red[0][tid] + red[1][tid] + red[2][tid] + red[3][tid];
}

__global__ __launch_bounds__(256) void scale_kernel(
        const float* __restrict__ Wg, const float* __restrict__ Wr,
        const float* __restrict__ g1, const float* __restrict__ b1,
        const float* __restrict__ g2, const float* __restrict__ b2,
        char* __restrict__ wsb, int fillw2) {
    const float* st = (const float*)(wsb + WS_ST);
    float* cf = (float*)(wsb + WS_CF);
    unsigned short* wf2 = (unsigned short*)(wsb + WS_WF2);
    __shared__ float cl[384];
    int tid = threadIdx.x;
    if (tid < 128) {
        int o = tid;
        const float inv_m = 1.0f / M_TOT;
        float mH = st[o] * inv_m,        vH = st[128 + o] * inv_m - mH * mH;
        float mR = st[256 + o] * inv_m,  vR = st[384 + o] * inv_m - mR * mR;
        float scH = g1[o] * rsqrtf(vH + EPS);
        float scR = g2[o] * rsqrtf(vR + EPS);
        float bC  = b1[o] + b2[o] - scH * mH - scR * mR;
        cl[o] = scH; cl[128 + o] = scR; cl[256 + o] = bC;
        if (blockIdx.x == 0) { cf[o] = scH; cf[128 + o] = scR; cf[256 + o] = bC; }
    }
    __syncthreads();
    if (!fillw2) return;
    for (int i = blockIdx.x * 256 + tid; i < 32768; i += gridDim.x * 256) {
        int on = i >> 12, kt = (i >> 9) & 7, l = (i >> 3) & 63, j = i & 7;
        int o = on * 16 + (l & 15);
        int kc = kt * 32 + ((l >> 4) << 3) + j;
        float v = (kc < 192) ? Wg[((kc >> 6) * COUT + o) * CIN + (kc & 63)] * cl[o]
                             : Wr[o * CIN + (kc - 192)] * cl[128 + o];
        wf2[i] = f2h(v);
    }
}

// MODE 0: stats only (fallback pass0). MODE 1: recompute + fused BN -> out (fallback pass1).
// MODE 2: stats + lane-interleaved coalesced f16 HR store (primary single pass).
template <int MODE>
__global__ __launch_bounds__(256, 2) void gcn_kernel(
        const float* __restrict__ x, char* __restrict__ wsb, float* __restrict__ out,
        float* __restrict__ part) {
    __shared__ __align__(16) _Float16 xa[64 * 256];   // [col][kc], XOR-swizzled, 32768 B
    __shared__ __align__(16) _Float16 xs[2][64][32];  // [t][c][v-pad], 8192 B
    char* xab = (char*)xa;

    const unsigned short* wf = (const unsigned short*)(wsb + (MODE == 1 ? WS_WF2 : WS_WF));
    const unsigned short* ae = (const unsigned short*)(wsb + WS_AEF);
    const float* cf = (const float*)(wsb + WS_CF);

    const int tid = threadIdx.x, wv = tid >> 6, l = tid & 63;
    const int l15 = l & 15, lq = l >> 4;

    half8 af[2][8];
#pragma unroll
    for (int on = 0; on < 2; ++on)
#pragma unroll
        for (int kt = 0; kt < 8; ++kt)
            af[on][kt] = *(const half8*)&wf[(((wv * 2 + on) * 8 + kt) * 64 + l) * 8];

    half8 aef[4][2];
#pragma unroll
    for (int k = 0; k < 4; ++k)
#pragma unroll
        for (int nt = 0; nt < 2; ++nt)
            aef[k][nt] = *(const half8*)&ae[((k * 2 + nt) * 64 + l) * 8];

    float bC2[2];
    if (MODE == 1) {
#pragma unroll
        for (int on = 0; on < 2; ++on)
            bC2[on] = cf[256 + wv * 32 + on * 16 + l15];
    }

    float sH[2], sH2[2], sR[2], sR2[2];
    if (MODE != 1) {
#pragma unroll
        for (int on = 0; on < 2; ++on) { sH[on] = 0; sH2[on] = 0; sR[on] = 0; sR2[on] = 0; }
    }

    // zero xs pads (v 25..31); staging only writes v<25
    for (int e = tid; e < 896; e += 256) {
        int t = e / 448, r = e % 448;
        xs[t][r / 7][25 + r % 7] = (_Float16)0.0f;
    }

    // Uniform staging: 1024 float4 per tile; tail float4s overlap (f0 = min(4i,46)).
    float4v pre[4];
    auto issue_pre = [&](int n_, int t0_) {
#pragma unroll
        for (int p = 0; p < 4; ++p) {
            int idx = tid + p * 256;
            int c = idx >> 4, i = idx & 15;
            int f0 = i * 4; f0 = f0 > 46 ? 46 : f0;
            const float* g = x + n_ * 480000 + c * 7500 + t0_ * 25 + f0;
            float4u v = *(const float4u*)g;
            pre[p][0] = v[0]; pre[p][1] = v[1]; pre[p][2] = v[2]; pre[p][3] = v[3];
        }
    };
    auto write_xs = [&]() {
#pragma unroll
        for (int p = 0; p < 4; ++p) {
            int idx = tid + p * 256;
            int c = idx >> 4, i = idx & 15;
            int f0 = i * 4; f0 = f0 > 46 ? 46 : f0;
#pragma unroll
            for (int s = 0; s < 4; ++s) {
                int f = f0 + s;
                int tsel = (f >= 25) ? 1 : 0;
                xs[tsel][c][f - tsel * 25] = (_Float16)pre[p][s];
            }
        }
    };

    const int tile0 = blockIdx.x * 3;
    { int n0 = tile0 / 150, t00 = (tile0 % 150) * 2; issue_pre(n0, t00); }
    write_xs();

    for (int it = 0; it < 3; ++it) {
        const int tile = tile0 + it;
        const int n = tile / 150, t0 = (tile % 150) * 2;
        bar_lds();  // xs ready; xa free

        const bool hn = (it < 2);
        if (hn) { int tl = tile + 1; issue_pre(tl / 150, (tl % 150) * 2); }

        // ---- stage1: xa[col][kc] pieces (k=3 identity -> raw X) ----
#pragma unroll
        for (int t = 0; t < 2; ++t) {
            half8 xf = *(const half8*)&xs[t][wv * 16 + l15][lq * 8];
#pragma unroll
            for (int k = 0; k < 4; ++k)
#pragma unroll
                for (int nt = 0; nt < 2; ++nt) {
                    float4v c4 = {0.0f, 0.0f, 0.0f, 0.0f};
                    c4 = mfma16(xf, aef[k][nt], c4);
                    int col = t * 32 + nt * 16 + l15;
                    int kcb = (k * 64 + wv * 16 + lq * 4) * 2;
                    u64 pk = ((u64)pk2(c4[2], c4[3]) << 32) | pk2(c4[0], c4[1]);
                    *(u64*)(xab + ((col << 9) + (kcb ^ ((col & 7) << 4)))) = pk;
                }
        }
        bar_lds();  // xa ready; xs free

        char* hrw = wsb + WS_HR + (size_t)tile * 28672 + wv * 7168;  // this wave's H block; R at +3584

        // ---- stage2 (transposed): C[col][o] ----
        float4v acc[4][2];
        if (MODE != 1) {
#pragma unroll
            for (int cm = 0; cm < 4; ++cm)
#pragma unroll
                for (int on = 0; on < 2; ++on) acc[cm][on] = {0.0f, 0.0f, 0.0f, 0.0f};
#pragma unroll
            for (int kt = 0; kt < 6; ++kt)
#pragma unroll
                for (int cm = 0; cm < 4; ++cm) {
                    int col = cm * 16 + l15;
                    half8 bf = *(const half8*)(xab + ((col << 9) +
                                   ((kt * 64 + lq * 16) ^ ((col & 7) << 4))));
                    acc[cm][0] = mfma16(bf, af[0][kt], acc[cm][0]);
                    acc[cm][1] = mfma16(bf, af[1][kt], acc[cm][1]);
                }
            // H flush: stats + lane-interleaved coalesced store (MODE 2)
#pragma unroll
            for (int cm = 0; cm < 4; ++cm)
#pragma unroll
                for (int on = 0; on < 2; ++on) {
#pragma unroll
                    for (int r = 0; r < 4; ++r) {
                        float h = acc[cm][on][r];
                        sH[on] += h; sH2[on] += h * h;
                    }
                    if (MODE == 2) {
                        u64 p = (u64)pk2(acc[cm][on][0], acc[cm][on][1]) |
                                ((u64)pk2(acc[cm][on][2], acc[cm][on][3]) << 32);
                        if (!(cm & 1)) {
                            *(u64*)(hrw + hr_off(cm, on) + l * 8) = p;
                        } else if (lq < 3) {
                            *(u64*)(hrw + hr_off(cm, on) + l * 8) = p;
                        }
                    }
                    acc[cm][on] = {0.0f, 0.0f, 0.0f, 0.0f};
                }
#pragma unroll
            for (int kt = 6; kt < 8; ++kt)
#pragma unroll
                for (int cm = 0; cm < 4; ++cm) {
                    int col = cm * 16 + l15;
                    half8 bf = *(const half8*)(xab + ((col << 9) +
                                   ((kt * 64 + lq * 16) ^ ((col & 7) << 4))));
                    acc[cm][0] = mfma16(bf, af[0][kt], acc[cm][0]);
                    acc[cm][1] = mfma16(bf, af[1][kt], acc[cm][1]);
                }
            // R flush
#pragma unroll
            for (int cm = 0; cm < 4; ++cm)
#pragma unroll
                for (int on = 0; on < 2; ++on) {
#pragma unroll
                    for (int r = 0; r < 4; ++r) {
                        float rv = acc[cm][on][r];
                        sR[on] += rv; sR2[on] += rv * rv;
                    }
                    if (MODE == 2) {
                        u64 p = (u64)pk2(acc[cm][on][0], acc[cm][on][1]) |
                                ((u64)pk2(acc[cm][on][2], acc[cm][on][3]) << 32);
                        if (!(cm & 1)) {
                            *(u64*)(hrw + 3584 + hr_off(cm, on) + l * 8) = p;
                        } else if (lq < 3) {
                            *(u64*)(hrw + 3584 + hr_off(cm, on) + l * 8) = p;
                        }
                    }
                }
        } else {
#pragma unroll
            for (int cm = 0; cm < 4; ++cm)
#pragma unroll
                for (int on = 0; on < 2; ++on)
#pragma unroll
                    for (int r = 0; r < 4; ++r) acc[cm][on][r] = bC2[on];
#pragma unroll
            for (int kt = 0; kt < 8; ++kt)
#pragma unroll
                for (int cm = 0; cm < 4; ++cm) {
                    int col = cm * 16 + l15;
                    half8 bf = *(const half8*)(xab + ((col << 9) +
                                   ((kt * 64 + lq * 16) ^ ((col & 7) << 4))));
                    acc[cm][0] = mfma16(bf, af[0][kt], acc[cm][0]);
                    acc[cm][1] = mfma16(bf, af[1][kt], acc[cm][1]);
                }
#pragma unroll
            for (int cm = 0; cm < 4; ++cm) {
                int t = t0 + (cm >> 1);
#pragma unroll
                for (int on = 0; on < 2; ++on) {
                    int o = wv * 32 + on * 16 + l15;
                    float* op = out + ((size_t)(n * COUT + o) * TT + t) * VV;
                    if (!(cm & 1)) {
                        *(float4u*)(op + lq * 4) = acc[cm][on];
                    } else if (lq < 2) {
                        *(float4u*)(op + 16 + lq * 4) = acc[cm][on];
                    } else if (lq == 2) {
                        op[24] = acc[cm][on][0];
                    }
                }
            }
        }

        if (hn) write_xs();

        if (it < 2) {
            __builtin_amdgcn_sched_barrier(0);
            if (MODE == 2) asm volatile("s_waitcnt vmcnt(16) lgkmcnt(0)" ::: "memory");
            else           asm volatile("s_waitcnt vmcnt(0) lgkmcnt(0)" ::: "memory");
            __builtin_amdgcn_s_barrier();
            __builtin_amdgcn_sched_barrier(0);
        }
    }

    if (MODE != 1) {
#pragma unroll
        for (int on = 0; on < 2; ++on) {
            sH[on]  += __shfl_xor(sH[on], 16);  sH[on]  += __shfl_xor(sH[on], 32);
            sH2[on] += __shfl_xor(sH2[on], 16); sH2[on] += __shfl_xor(sH2[on], 32);
            sR[on]  += __shfl_xor(sR[on], 16);  sR[on]  += __shfl_xor(sR[on], 32);
            sR2[on] += __shfl_xor(sR2[on], 16); sR2[on] += __shfl_xor(sR2[on], 32);
        }
        if (l < 16) {
            float* pb = part + (size_t)blockIdx.x * 512;
#pragma unroll
            for (int on = 0; on < 2; ++on) {
                int o = wv * 32 + on * 16 + l15;
                pb[o]       = sH[on];
                pb[128 + o] = sH2[on];
                pb[256 + o] = sR[on];
                pb[384 + o] = sR2[on];
            }
        }
    }
}

// BN apply: block per tile. Coalesced u64 load of 28672 B -> LDS, then linear out writes.
__global__ __launch_bounds__(256) void bn_apply(const char* __restrict__ wsb,
                                                float* __restrict__ out) {
    __shared__ u64 lds[3584];
    const float* cf = (const float*)(wsb + WS_CF);
    const int tile = blockIdx.x;
    const int n = tile / 150, t0 = (tile % 150) * 2;
    const int tid = threadIdx.x;

    const u64* src = (const u64*)(wsb + WS_HR + (size_t)tile * 28672);
#pragma unroll
    for (int i = 0; i < 14; ++i) lds[tid + i * 256] = src[tid + i * 256];
    __syncthreads();

#pragma unroll
    for (int i = 0; i < 7; ++i) {
        int j2 = tid + i * 256;          // 1792 = 256 rows x 7 quarters
        int row = j2 / 7, q = j2 - row * 7;
        int o = row >> 1, t = row & 1;
        int v0 = (q < 6) ? q * 4 : 24;
        int cm = t * 2 + (v0 >> 4);
        int lq = (v0 & 15) >> 2;
        int ll = lq * 16 + (o & 15);
        int wv = o >> 5, on = (o >> 4) & 1;
        int offq = (cm & 1) ? (256 + (cm >> 1) * 96 + on * 48)
                            : ((cm >> 1) * 128 + on * 64);
        u64 h64 = lds[wv * 896 + offq + ll];
        u64 r64 = lds[wv * 896 + 448 + offq + ll];
        half4v h4 = __builtin_bit_cast(half4v, h64);
        half4v r4 = __builtin_bit_cast(half4v, r64);
        float scH = cf[o], scR = cf[128 + o], bC = cf[256 + o];
        float* op = out + ((size_t)(n * COUT + o) * TT + t0 + t) * VV + v0;
        if (q < 6) {
            float4u v;
#pragma unroll
            for (int k = 0; k < 4; ++k)
                v[k] = scH * (float)h4[k] + scR * (float)r4[k] + bC;
            *(float4u*)op = v;
        } else {
            op[0] = scH * (float)h4[0] + scR * (float)r4[0] + bC;
        }
    }
}

extern "C" void kernel_launch(void* const* d_in, const int* in_sizes, int n_in,
                              void* d_out, int out_size, void* d_ws, size_t ws_size,
                              hipStream_t stream) {
    const float* x        = (const float*)d_in[0];
    const float* A        = (const float*)d_in[1];
    const float* ga       = (const float*)d_in[2];
    const float* Wg       = (const float*)d_in[3];
    const float* bn_gamma = (const float*)d_in[5];
    const float* bn_beta  = (const float*)d_in[6];
    const float* Wr       = (const float*)d_in[7];
    const float* rbn_g    = (const float*)d_in[9];
    const float* rbn_b    = (const float*)d_in[10];
    char* wsb  = (char*)d_ws;
    float* out = (float*)d_out;

    const bool primary = ws_size >= (size_t)WS_NEED + 4096;
    float* partP = (float*)(wsb + WS_PARTP);
    float* partF = (float*)(wsb + WS_HR);

    prep_kernel<<<64, 256, 0, stream>>>(A, ga, Wg, Wr, wsb);
    if (primary) {
        gcn_kernel<2><<<NBLK, 256, 0, stream>>>(x, wsb, nullptr, partP);
        red_kernel<<<128, 256, 0, stream>>>(partP, wsb);
        scale_kernel<<<64, 256, 0, stream>>>(Wg, Wr, bn_gamma, bn_beta, rbn_g, rbn_b, wsb, 0);
        bn_apply<<<NTILE, 256, 0, stream>>>(wsb, out);
    } else {
        gcn_kernel<0><<<NBLK, 256, 0, stream>>>(x, wsb, nullptr, partF);
        red_kernel<<<128, 256, 0, stream>>>(partF, wsb);
        scale_kernel<<<64, 256, 0, stream>>>(Wg, Wr, bn_gamma, bn_beta, rbn_g, rbn_b, wsb, 1);
        gcn_kernel<1><<<NBLK, 256, 0, stream>>>(x, wsb, out, partF);
    }
}